// Round 6
// baseline (294.725 us; speedup 1.0000x reference)
//
#include <hip/hip_runtime.h>

// INSTRUMENTATION ROUND.
// Kernel 1 (fast_lds): exact round-2 best kernel -> d_out (correctness+timing).
// Kernel 2 (heavy_lds): same structure, k-loop repeated REP=8x -> d_ws.
// Kernel 3 (heavy_lane): round-5 readlane structure, REP=8x -> d_ws+4MB.
// The heavies run ~8x the true kernel time, forcing them into rocprof's
// top-5 with real counters (VALUBusy, LDS conflicts, occupancy), and
// heavy_dur/8 measures the true per-pass kernel cost independent of the
// harness's 42us workspace-poison fill.

typedef float v2f __attribute__((ext_vector_type(2)));

constexpr int B = 512;
constexpr int K = 64;
constexpr int C = 2048;
constexpr int BLOCK = 256;
constexpr int HALVES = 2;
constexpr int CH = C / HALVES;
constexpr int REP = 8;

__device__ __forceinline__ float rdlane(float v, int k) {
    return __uint_as_float(__builtin_amdgcn_readlane(__float_as_uint(v), k));
}

// ---------------- fast (round-2 exact) ----------------
__global__ __launch_bounds__(BLOCK, 4) void fast_lds(
    const float* __restrict__ mo, const float* __restrict__ X,
    float* __restrict__ out)
{
    __shared__ float4 P[K][2];
    const int bid = blockIdx.x;
    const int b = bid >> 1, h = bid & 1, t = threadIdx.x;

    if (t < K) {
        const float* p = mo + ((size_t)(b * K + t)) * 6;
        const float w = p[0], m1 = p[1], m2 = p[2], s1 = p[3], s2 = p[4], r = p[5];
        const float omr2 = fmaf(-r, r, 1.0f);
        const float inv = 1.0f / omr2;
        const float a2 = 0.7213475204444817f * inv;
        const float sc = sqrtf(a2);
        const float is1 = sc / s1, is2 = sc / s2;
        const float wn = w * 0.15915494309189535f / (s1 * s2 * sqrtf(omr2));
        P[t][0] = make_float4(is1, is2, m1 * is1, m2 * is2);
        P[t][1] = make_float4(2.0f * r, wn, 0.0f, 0.0f);
    }
    __syncthreads();

    const float4* Xb = (const float4*)(X + (size_t)b * C * 2 + (size_t)h * CH * 2);
    const float4 xv0 = Xb[t];
    const float4 xv1 = Xb[t + BLOCK];
    v2f xs[2] = { {xv0.x, xv0.z}, {xv1.x, xv1.z} };
    v2f ys[2] = { {xv0.y, xv0.w}, {xv1.y, xv1.w} };
    v2f acc[2] = { {0.0f, 0.0f}, {0.0f, 0.0f} };

#pragma unroll 4
    for (int k = 0; k < K; ++k) {
        const float4 p0 = P[k][0];
        const float4 p1 = P[k][1];
        const v2f vis1 = { p0.x, p0.x }, vis2 = { p0.y, p0.y };
        const v2f vnm1 = { -p0.z, -p0.z }, vnm2 = { -p0.w, -p0.w };
        const v2f v2r = { p1.x, p1.x }, vwn = { p1.y, p1.y };
#pragma unroll
        for (int j = 0; j < 2; ++j) {
            const v2f dx = __builtin_elementwise_fma(xs[j], vis1, vnm1);
            const v2f dy = __builtin_elementwise_fma(ys[j], vis2, vnm2);
            const v2f pq = dx * dy;
            v2f u = dx * dx;
            u = __builtin_elementwise_fma(dy, dy, u);
            const v2f e = __builtin_elementwise_fma(v2r, pq, -u);
            v2f ex;
            ex.x = __builtin_amdgcn_exp2f(e.x);
            ex.y = __builtin_amdgcn_exp2f(e.y);
            acc[j] = __builtin_elementwise_fma(vwn, ex, acc[j]);
        }
    }

    float2* ob = (float2*)(out + (size_t)b * C + (size_t)h * CH);
    ob[t] = make_float2(acc[0].x, acc[0].y);
    ob[t + BLOCK] = make_float2(acc[1].x, acc[1].y);
}

// ---------------- heavy: LDS structure, REP x ----------------
__global__ __launch_bounds__(BLOCK, 4) void heavy_lds(
    const float* __restrict__ mo, const float* __restrict__ X,
    float* __restrict__ out)
{
    __shared__ float4 P[K][2];
    const int bid = blockIdx.x;
    const int b = bid >> 1, h = bid & 1, t = threadIdx.x;

    if (t < K) {
        const float* p = mo + ((size_t)(b * K + t)) * 6;
        const float w = p[0], m1 = p[1], m2 = p[2], s1 = p[3], s2 = p[4], r = p[5];
        const float omr2 = fmaf(-r, r, 1.0f);
        const float inv = 1.0f / omr2;
        const float a2 = 0.7213475204444817f * inv;
        const float sc = sqrtf(a2);
        const float is1 = sc / s1, is2 = sc / s2;
        const float wn = w * 0.15915494309189535f / (s1 * s2 * sqrtf(omr2));
        P[t][0] = make_float4(is1, is2, m1 * is1, m2 * is2);
        P[t][1] = make_float4(2.0f * r, wn, 0.0f, 0.0f);
    }
    __syncthreads();

    const float4* Xb = (const float4*)(X + (size_t)b * C * 2 + (size_t)h * CH * 2);
    const float4 xv0 = Xb[t];
    const float4 xv1 = Xb[t + BLOCK];
    v2f xs[2] = { {xv0.x, xv0.z}, {xv1.x, xv1.z} };
    v2f ys[2] = { {xv0.y, xv0.w}, {xv1.y, xv1.w} };
    v2f acc[2] = { {0.0f, 0.0f}, {0.0f, 0.0f} };

#pragma unroll 1
    for (int rep = 0; rep < REP; ++rep) {
        // per-rep perturbation: prevents hoisting the exp chains across reps
        const float eps = (float)rep * 1e-30f;
        const v2f ve = { eps, eps };
        const v2f px[2] = { xs[0] + ve, xs[1] + ve };
#pragma unroll 4
        for (int k = 0; k < K; ++k) {
            const float4 p0 = P[k][0];
            const float4 p1 = P[k][1];
            const v2f vis1 = { p0.x, p0.x }, vis2 = { p0.y, p0.y };
            const v2f vnm1 = { -p0.z, -p0.z }, vnm2 = { -p0.w, -p0.w };
            const v2f v2r = { p1.x, p1.x }, vwn = { p1.y, p1.y };
#pragma unroll
            for (int j = 0; j < 2; ++j) {
                const v2f dx = __builtin_elementwise_fma(px[j], vis1, vnm1);
                const v2f dy = __builtin_elementwise_fma(ys[j], vis2, vnm2);
                const v2f pq = dx * dy;
                v2f u = dx * dx;
                u = __builtin_elementwise_fma(dy, dy, u);
                const v2f e = __builtin_elementwise_fma(v2r, pq, -u);
                v2f ex;
                ex.x = __builtin_amdgcn_exp2f(e.x);
                ex.y = __builtin_amdgcn_exp2f(e.y);
                acc[j] = __builtin_elementwise_fma(vwn, ex, acc[j]);
            }
        }
    }

    float2* ob = (float2*)(out + (size_t)b * C + (size_t)h * CH);
    ob[t] = make_float2(acc[0].x, acc[0].y);
    ob[t + BLOCK] = make_float2(acc[1].x, acc[1].y);
}

// ---------------- heavy: readlane structure, REP x ----------------
__global__ __launch_bounds__(BLOCK) void heavy_lane(
    const float* __restrict__ mo, const float* __restrict__ X,
    float* __restrict__ out)
{
    const int bid = blockIdx.x;
    const int b = bid >> 1, h = bid & 1, t = threadIdx.x;
    const int lane = t & 63;

    const float4* Xb = (const float4*)(X + (size_t)b * C * 2 + (size_t)h * CH * 2);
    const float4 xv0 = Xb[t];
    const float4 xv1 = Xb[t + BLOCK];

    const float* p = mo + ((size_t)(b * K + lane)) * 6;
    const float w = p[0], m1 = p[1], m2 = p[2], s1 = p[3], s2 = p[4], r = p[5];
    const float omr2 = fmaf(-r, r, 1.0f);
    const float inv = 1.0f / omr2;
    const float a2 = 0.7213475204444817f * inv;
    const float sc = sqrtf(a2);
    const float cIS1 = sc / s1, cIS2 = sc / s2;
    const float cNM1 = -(m1 * cIS1), cNM2 = -(m2 * cIS2);
    const float cR2 = 2.0f * r;
    const float cWN = w * 0.15915494309189535f * sqrtf(inv) / (s1 * s2);

    const v2f xs0 = { xv0.x, xv0.z }, ys0 = { xv0.y, xv0.w };
    const v2f xs1 = { xv1.x, xv1.z }, ys1 = { xv1.y, xv1.w };
    v2f acc0 = { 0.0f, 0.0f }, acc1 = { 0.0f, 0.0f };

#pragma unroll 1
    for (int rep = 0; rep < REP; ++rep) {
        const float eps = (float)rep * 1e-30f;
        const v2f ve = { eps, eps };
        const v2f px0 = xs0 + ve, px1 = xs1 + ve;
#pragma unroll 8
        for (int k = 0; k < K; ++k) {
            const float fIS1 = rdlane(cIS1, k);
            const float fIS2 = rdlane(cIS2, k);
            const float fNM1 = rdlane(cNM1, k);
            const float fNM2 = rdlane(cNM2, k);
            const float fR2  = rdlane(cR2, k);
            const float fWN  = rdlane(cWN, k);
            const v2f IS1 = { fIS1, fIS1 }, IS2 = { fIS2, fIS2 };
            const v2f NM1 = { fNM1, fNM1 }, NM2 = { fNM2, fNM2 };
            const v2f R2v = { fR2, fR2 }, WN = { fWN, fWN };
            {
                const v2f dx = __builtin_elementwise_fma(px0, IS1, NM1);
                const v2f dy = __builtin_elementwise_fma(ys0, IS2, NM2);
                const v2f pq = dx * dy;
                v2f u = dx * dx;
                u = __builtin_elementwise_fma(dy, dy, u);
                const v2f e = __builtin_elementwise_fma(R2v, pq, -u);
                v2f ex;
                ex.x = __builtin_amdgcn_exp2f(e.x);
                ex.y = __builtin_amdgcn_exp2f(e.y);
                acc0 = __builtin_elementwise_fma(WN, ex, acc0);
            }
            {
                const v2f dx = __builtin_elementwise_fma(px1, IS1, NM1);
                const v2f dy = __builtin_elementwise_fma(ys1, IS2, NM2);
                const v2f pq = dx * dy;
                v2f u = dx * dx;
                u = __builtin_elementwise_fma(dy, dy, u);
                const v2f e = __builtin_elementwise_fma(R2v, pq, -u);
                v2f ex;
                ex.x = __builtin_amdgcn_exp2f(e.x);
                ex.y = __builtin_amdgcn_exp2f(e.y);
                acc1 = __builtin_elementwise_fma(WN, ex, acc1);
            }
        }
    }

    float2* ob = (float2*)(out + (size_t)b * C + (size_t)h * CH);
    ob[t] = make_float2(acc0.x, acc0.y);
    ob[t + BLOCK] = make_float2(acc1.x, acc1.y);
}

extern "C" void kernel_launch(void* const* d_in, const int* in_sizes, int n_in,
                              void* d_out, int out_size, void* d_ws, size_t ws_size,
                              hipStream_t stream) {
    const float* mo = (const float*)d_in[0];
    const float* X  = (const float*)d_in[1];
    float* out      = (float*)d_out;
    float* ws0      = (float*)d_ws;                    // heavy_lds sink (4 MB)
    float* ws1      = (float*)d_ws + (size_t)B * C;    // heavy_lane sink (4 MB)

    fast_lds  <<<dim3(B * HALVES), dim3(BLOCK), 0, stream>>>(mo, X, out);
    heavy_lds <<<dim3(B * HALVES), dim3(BLOCK), 0, stream>>>(mo, X, ws0);
    heavy_lane<<<dim3(B * HALVES), dim3(BLOCK), 0, stream>>>(mo, X, ws1);
}

// Round 7
// 71.570 us; speedup vs baseline: 4.1180x; 4.1180x over previous
//
#include <hip/hip_runtime.h>

// out[b,c] = sum_k w[b,k] * BivariateNormalPDF(X[b,c]; params[b,k])
// B=512, K=64, C=2048.
//
// Round 7: R2 skeleton (1024 blocks, 4 pts/thread, LDS broadcast) with the
// exponent expanded as a log2-domain bivariate quadratic:
//   e = A x^2 + B y^2 + C xy + D x + E y + F,   acc += exp2(e)
// where (per k):  g = 0.5*log2e/(1-r^2), p = g/s1^2, q = g/s2^2,
//   s = 2 r g/(s1 s2), A=-p, B=-q, C=s, D=2p m1 - s m2, E=2q m2 - s m1,
//   F = log2(w/(2pi s1 s2 sqrt(1-r^2))) - p m1^2 - q m2^2 + s m1 m2.
// x^2, y^2, xy are hoisted out of the k-loop. Coefficients live in LDS
// pre-duplicated as pairs so every v_pk_fma_f32 operand is a plain register
// pair straight from ds_read_b128 -> no splat movs.
// Inner cost per k-iter per wave: 12 pk + 4 exp + 3 ds_read_b128.

typedef float v2f __attribute__((ext_vector_type(2)));

constexpr int B = 512;
constexpr int K = 64;
constexpr int C = 2048;
constexpr int BLOCK = 256;
constexpr int HALVES = 2;        // each batch's C range split across 2 blocks
constexpr int CH = C / HALVES;   // 1024 points per block -> 4 per thread

__global__ __launch_bounds__(BLOCK, 4) void mixture_kernel(
    const float* __restrict__ mo,   // (B, K, 6)
    const float* __restrict__ X,    // (B, C, 2)
    float* __restrict__ out)        // (B, C)
{
    __shared__ float4 P[K][3];      // [A,A,B,B], [C,C,D,D], [E,E,F,F]

    const int bid = blockIdx.x;
    const int b   = bid >> 1;
    const int h   = bid & 1;
    const int t   = threadIdx.x;

    if (t < K) {
        const float* p6 = mo + ((size_t)(b * K + t)) * 6;
        const float w  = p6[0];
        const float m1 = p6[1];
        const float m2 = p6[2];
        const float s1 = p6[3];
        const float s2 = p6[4];
        const float r  = p6[5];

        const float omr2 = fmaf(-r, r, 1.0f);
        const float inv  = 1.0f / omr2;
        const float g    = 0.7213475204444817f * inv;   // 0.5*log2(e)/omr2
        const float i1   = 1.0f / s1;
        const float i2   = 1.0f / s2;
        const float p    = g * i1 * i1;
        const float q    = g * i2 * i2;
        const float s    = 2.0f * r * g * i1 * i2;
        const float A    = -p;
        const float Bc   = -q;
        const float Cc   = s;
        const float D    = fmaf(2.0f * p, m1, -s * m2);
        const float E    = fmaf(2.0f * q, m2, -s * m1);
        const float wn   = w * 0.15915494309189535f * i1 * i2 * sqrtf(inv);
        const float L    = log2f(fmaxf(wn, 1e-37f));
        const float F    = fmaf(-p, m1 * m1, fmaf(-q, m2 * m2, fmaf(s, m1 * m2, L)));

        P[t][0] = make_float4(A, A, Bc, Bc);
        P[t][1] = make_float4(Cc, Cc, D, D);
        P[t][2] = make_float4(E, E, F, F);
    }
    __syncthreads();

    // 4 points/thread: 2 coalesced float4 loads, repacked as (x,x)/(y,y)
    // pairs; x^2, y^2, x*y hoisted (one-time, 6 pk ops).
    const float4* Xb = (const float4*)(X + (size_t)b * C * 2 + (size_t)h * CH * 2);
    const float4 xv0 = Xb[t];
    const float4 xv1 = Xb[t + BLOCK];

    const v2f xp[2]  = { {xv0.x, xv0.z}, {xv1.x, xv1.z} };
    const v2f yp[2]  = { {xv0.y, xv0.w}, {xv1.y, xv1.w} };
    const v2f xx[2]  = { xp[0] * xp[0], xp[1] * xp[1] };
    const v2f yy[2]  = { yp[0] * yp[0], yp[1] * yp[1] };
    const v2f xy[2]  = { xp[0] * yp[0], xp[1] * yp[1] };
    v2f acc[2] = { {0.0f, 0.0f}, {0.0f, 0.0f} };

#pragma unroll 4
    for (int k = 0; k < K; ++k) {
        const float4 c0 = P[k][0];   // A,A,B,B   (LDS broadcast)
        const float4 c1 = P[k][1];   // C,C,D,D
        const float4 c2 = P[k][2];   // E,E,F,F
        const v2f A2 = { c0.x, c0.y };
        const v2f B2 = { c0.z, c0.w };
        const v2f C2 = { c1.x, c1.y };
        const v2f D2 = { c1.z, c1.w };
        const v2f E2 = { c2.x, c2.y };
        const v2f F2 = { c2.z, c2.w };

#pragma unroll
        for (int j = 0; j < 2; ++j) {
            v2f e = __builtin_elementwise_fma(A2, xx[j], F2);
            e     = __builtin_elementwise_fma(B2, yy[j], e);
            e     = __builtin_elementwise_fma(C2, xy[j], e);
            e     = __builtin_elementwise_fma(D2, xp[j], e);
            e     = __builtin_elementwise_fma(E2, yp[j], e);
            v2f ex;
            ex.x = __builtin_amdgcn_exp2f(e.x);
            ex.y = __builtin_amdgcn_exp2f(e.y);
            acc[j] = acc[j] + ex;
        }
    }

    float2* ob = (float2*)(out + (size_t)b * C + (size_t)h * CH);
    ob[t]         = make_float2(acc[0].x, acc[0].y);
    ob[t + BLOCK] = make_float2(acc[1].x, acc[1].y);
}

extern "C" void kernel_launch(void* const* d_in, const int* in_sizes, int n_in,
                              void* d_out, int out_size, void* d_ws, size_t ws_size,
                              hipStream_t stream) {
    const float* mo = (const float*)d_in[0];   // (B,K,6)
    const float* X  = (const float*)d_in[1];   // (B,C,2)
    float* out      = (float*)d_out;           // (B,C)

    mixture_kernel<<<dim3(B * HALVES), dim3(BLOCK), 0, stream>>>(mo, X, out);
}

// Round 8
// 70.341 us; speedup vs baseline: 4.1899x; 1.0175x over previous
//
#include <hip/hip_runtime.h>

// out[b,c] = sum_k w[b,k] * BivariateNormalPDF(X[b,c]; params[b,k])
// B=512, K=64, C=2048.
//
// Round 8: R7 quadratic-form kernel with coefficient LDS reads cut 3 -> 2
// ds_read_b128 per k-iter (LDS pipe is the measured bottleneck at ~10us).
// Exponent in log2 domain: e = A x^2 + B y^2 + C xy + D x + E y + F,
//   acc += exp2(e)  (wn folded into F; x^2,y^2,xy hoisted per thread).
// Coefficients stored unduplicated [A,B,C,D][E,F,-,-]; pair-splats are
// register-level (VOP3P op_sel folds them; worst case 6 v_mov under the
// LDS ceiling). 1024 blocks (4 blocks/CU), 256 threads, 4 points/thread.

typedef float v2f __attribute__((ext_vector_type(2)));

constexpr int B = 512;
constexpr int K = 64;
constexpr int C = 2048;
constexpr int BLOCK = 256;
constexpr int HALVES = 2;        // each batch's C range split across 2 blocks
constexpr int CH = C / HALVES;   // 1024 points per block -> 4 per thread

__device__ __forceinline__ v2f splat(float v) { return (v2f){v, v}; }

__global__ __launch_bounds__(BLOCK, 4) void mixture_kernel(
    const float* __restrict__ mo,   // (B, K, 6)
    const float* __restrict__ X,    // (B, C, 2)
    float* __restrict__ out)        // (B, C)
{
    __shared__ float4 P[K][2];      // [A,B,C,D], [E,F,-,-]

    const int bid = blockIdx.x;
    const int b   = bid >> 1;
    const int h   = bid & 1;
    const int t   = threadIdx.x;

    if (t < K) {
        const float* p6 = mo + ((size_t)(b * K + t)) * 6;
        const float w  = p6[0];
        const float m1 = p6[1];
        const float m2 = p6[2];
        const float s1 = p6[3];
        const float s2 = p6[4];
        const float r  = p6[5];

        const float omr2 = fmaf(-r, r, 1.0f);
        const float inv  = 1.0f / omr2;
        const float g    = 0.7213475204444817f * inv;   // 0.5*log2(e)/omr2
        const float i1   = 1.0f / s1;
        const float i2   = 1.0f / s2;
        const float p    = g * i1 * i1;
        const float q    = g * i2 * i2;
        const float s    = 2.0f * r * g * i1 * i2;
        const float A    = -p;
        const float Bc   = -q;
        const float Cc   = s;
        const float D    = fmaf(2.0f * p, m1, -s * m2);
        const float E    = fmaf(2.0f * q, m2, -s * m1);
        const float wn   = w * 0.15915494309189535f * i1 * i2 * sqrtf(inv);
        const float L    = log2f(fmaxf(wn, 1e-37f));
        const float F    = fmaf(-p, m1 * m1, fmaf(-q, m2 * m2, fmaf(s, m1 * m2, L)));

        P[t][0] = make_float4(A, Bc, Cc, D);
        P[t][1] = make_float4(E, F, 0.0f, 0.0f);
    }
    __syncthreads();

    // 4 points/thread: 2 coalesced float4 loads, repacked as (x,x)/(y,y)
    // pairs; x^2, y^2, x*y hoisted (one-time).
    const float4* Xb = (const float4*)(X + (size_t)b * C * 2 + (size_t)h * CH * 2);
    const float4 xv0 = Xb[t];
    const float4 xv1 = Xb[t + BLOCK];

    const v2f xp[2]  = { {xv0.x, xv0.z}, {xv1.x, xv1.z} };
    const v2f yp[2]  = { {xv0.y, xv0.w}, {xv1.y, xv1.w} };
    const v2f xx[2]  = { xp[0] * xp[0], xp[1] * xp[1] };
    const v2f yy[2]  = { yp[0] * yp[0], yp[1] * yp[1] };
    const v2f xy[2]  = { xp[0] * yp[0], xp[1] * yp[1] };
    v2f acc[2] = { {0.0f, 0.0f}, {0.0f, 0.0f} };

#pragma unroll 4
    for (int k = 0; k < K; ++k) {
        const float4 c0 = P[k][0];   // A,B,C,D   (LDS broadcast)
        const float4 c1 = P[k][1];   // E,F,-,-
        const v2f A2 = splat(c0.x);
        const v2f B2 = splat(c0.y);
        const v2f C2 = splat(c0.z);
        const v2f D2 = splat(c0.w);
        const v2f E2 = splat(c1.x);
        const v2f F2 = splat(c1.y);

#pragma unroll
        for (int j = 0; j < 2; ++j) {
            v2f e = __builtin_elementwise_fma(A2, xx[j], F2);
            e     = __builtin_elementwise_fma(B2, yy[j], e);
            e     = __builtin_elementwise_fma(C2, xy[j], e);
            e     = __builtin_elementwise_fma(D2, xp[j], e);
            e     = __builtin_elementwise_fma(E2, yp[j], e);
            v2f ex;
            ex.x = __builtin_amdgcn_exp2f(e.x);
            ex.y = __builtin_amdgcn_exp2f(e.y);
            acc[j] = acc[j] + ex;
        }
    }

    float2* ob = (float2*)(out + (size_t)b * C + (size_t)h * CH);
    ob[t]         = make_float2(acc[0].x, acc[0].y);
    ob[t + BLOCK] = make_float2(acc[1].x, acc[1].y);
}

extern "C" void kernel_launch(void* const* d_in, const int* in_sizes, int n_in,
                              void* d_out, int out_size, void* d_ws, size_t ws_size,
                              hipStream_t stream) {
    const float* mo = (const float*)d_in[0];   // (B,K,6)
    const float* X  = (const float*)d_in[1];   // (B,C,2)
    float* out      = (float*)d_out;           // (B,C)

    mixture_kernel<<<dim3(B * HALVES), dim3(BLOCK), 0, stream>>>(mo, X, out);
}